// Round 2
// baseline (124.856 us; speedup 1.0000x reference)
//
#include <hip/hip_runtime.h>

#define T_STEPS 128
#define DIM 1024
#define ODE_UNFOLDS 6
#define EPS 1e-8f
#define L2E 1.44269504088896340736f

typedef float v2f __attribute__((ext_vector_type(2)));

__device__ __forceinline__ float fexp2(float x) { return __builtin_amdgcn_exp2f(x); }
__device__ __forceinline__ float frcp(float x)  { return __builtin_amdgcn_rcpf(x); }
__device__ __forceinline__ v2f fma2(v2f a, v2f b, v2f c) {
  return __builtin_elementwise_fma(a, b, c);   // -> v_pk_fma_f32
}

__device__ __forceinline__ float softplus_init(float x) {
  // init-only (once per thread); inputs in (0,1] so no overflow concerns
  return log2f(1.0f + exp2f(x * L2E)) * (1.0f / L2E);
}

// swap adjacent lane pairs (0<->1, 2<->3, ...): v_mov_b32_dpp quad_perm:[1,0,3,2]
__device__ __forceinline__ float swap_adj(float x) {
  int y = __builtin_amdgcn_mov_dpp(__float_as_int(x), 0xB1, 0xF, 0xF, true);
  return __int_as_float(y);
}

__global__ __launch_bounds__(256) void memcell_kernel(
    const float* __restrict__ inputs,      // (B,T,DIM)
    const float* __restrict__ gleak,       // (U)
    const float* __restrict__ vleak,       // (U)
    const float* __restrict__ cm,          // (U)
    const float* __restrict__ w,           // (U,2)
    const float* __restrict__ sigma,       // (U,2)
    const float* __restrict__ mu,          // (U,2)
    const float* __restrict__ erev,        // (U,2)
    const float* __restrict__ sens_w,      // (U)
    const float* __restrict__ sens_sigma,  // (U)
    const float* __restrict__ sens_mu,     // (U)
    const float* __restrict__ sens_erev,   // (U)
    const float* __restrict__ input_w,     // (DIM)
    const float* __restrict__ input_b,     // (DIM)
    const float* __restrict__ output_w,    // (DIM)
    const float* __restrict__ output_b,    // (DIM)
    float* __restrict__ out)               // (B,DIM)
{
  const int tid  = blockIdx.x * blockDim.x + threadIdx.x;  // [0, B*U)
  const int p    = tid >> 1;          // chain index: b*DIM + col
  const int half = tid & 1;           // 0: unit=col, 1: unit=col+DIM
  const int b    = p >> 10;           // DIM == 1024
  const int col  = p & (DIM - 1);
  const int u    = col + (half << 10);

  // ---- per-thread constants ----
  const float spw0  = softplus_init(w[2*u]);
  const float spw1  = softplus_init(w[2*u+1]);
  const float spw0e = spw0 * erev[2*u];
  const float spw1e = spw1 * erev[2*u+1];
  const float sg0   = sigma[2*u],  sg1 = sigma[2*u+1];
  const float mu0   = mu[2*u],     mu1 = mu[2*u+1];
  // sigmoid((v-mu)*sg) = 1/(1 + exp2(fma(v, -sg*L2E, mu*sg*L2E)))
  const float negA0 = -sg0 * L2E,  B0c = mu0 * sg0 * L2E;
  const float negA1 = -sg1 * L2E,  B1c = mu1 * sg1 * L2E;
  // cross constants: each lane computes the exp2 its PARTNER needs
  // (partner's synapse-1 takes MY v as input, with partner's mu1/sg1)
  const float negA1x = swap_adj(negA1);
  const float B1x    = swap_adj(B1c);
  const float gl    = softplus_init(gleak[u]);
  const float glv   = gl * vleak[u];
  const float cmt   = softplus_init(cm[u]) * (float)ODE_UNFOLDS;
  const float dbase = cmt + gl + EPS;
  const float spsw  = softplus_init(sens_w[u]);
  const float ssg   = sens_sigma[u];
  const float negAs = -ssg * L2E,  Bsc = sens_mu[u] * ssg * L2E;
  const float serev = sens_erev[u];
  const float iw    = input_w[col];
  const float ib    = input_b[col];
  const v2f spk1 = {spw1e, spw1};
  const v2f spk0 = {spw0e, spw0};

  // sensory synapse for one step: depends ONLY on x (not v) -> pipelined ahead
  auto sens = [&](float xr) -> v2f {
    const float x  = fmaf(xr, iw, ib);
    const float ts = fexp2(fmaf(x, negAs, Bsc));
    const float s  = spsw * frcp(1.0f + ts);
    v2f r; r.x = fmaf(s, serev, glv);   // glv + num_s
    r.y = dbase + s;                    // cmt + gl + eps + den_s
    return r;
  };

  const float* xp = inputs + ((size_t)b * T_STEPS) * DIM + col;

  // 8-step-deep x pipeline: cur = steps [tb..tb+3], nxt = [tb+4..tb+7]
  float cur0 = xp[0 * DIM], cur1 = xp[1 * DIM], cur2 = xp[2 * DIM], cur3 = xp[3 * DIM];
  float nxt0 = xp[4 * DIM], nxt1 = xp[5 * DIM], nxt2 = xp[6 * DIM], nxt3 = xp[7 * DIM];

  v2f nd = sens(cur0);                // {ns, ds} for step 0
  float nume = 0.0f, rd = 1.0f;       // v = nume * rd = 0

  for (int tb = 0; tb < T_STEPS; tb += 4) {
    float l0 = 0.f, l1 = 0.f, l2 = 0.f, l3 = 0.f;
    const bool more = (tb + 8) < T_STEPS;
    if (more) {
      const float* nx = xp + (size_t)(tb + 8) * DIM;
      l0 = nx[0 * DIM]; l1 = nx[1 * DIM]; l2 = nx[2 * DIM]; l3 = nx[3 * DIM];
    }
    #pragma unroll
    for (int j = 0; j < 4; ++j) {
      // x for NEXT step's sensory (independent work -> fills latency shadows)
      const float xn = (j == 0) ? cur1 : (j == 1) ? cur2 : (j == 2) ? cur3 : nxt0;
      const v2f nd_next = sens(xn);
      #pragma unroll
      for (int k = 0; k < ODE_UNFOLDS; ++k) {
        // v = nume*rd, but fold the mul into the exp2 args so the
        // nume*negA muls issue during rcp's flight (shorter carried path)
        const float nnc  = nume * negA1x;
        const float nn0  = nume * negA0;
        const float tc   = fexp2(fmaf(nnc, rd, B1x));   // partner's t1
        const float t0   = fexp2(fmaf(nn0, rd, B0c));   // own t0
        const float v    = nume * rd;                   // off critical path
        const float t1   = swap_adj(tc);                // exchange AFTER exp2
        v2f a; a.x = t0; a.y = t1;
        a = a + 1.0f;                                   // pk_add: {a0, a1}
        const float D = a.x * a.y;
        v2f P = spk1 * a.x;                             // {spw1e*a0, spw1*a0}
        P = fma2(spk0, (v2f){a.y, a.y}, P);             // {E, S}
        v2f q; q.x = fmaf(cmt, v, nd.x); q.y = nd.y;    // {numerN, ds}
        const v2f ND = fma2(q, (v2f){D, D}, P);         // {nume, deno}
        nume = ND.x;
        rd   = frcp(ND.y);
      }
      nd = nd_next;
    }
    cur0 = nxt0; cur1 = nxt1; cur2 = nxt2; cur3 = nxt3;
    if (more) { nxt0 = l0; nxt1 = l1; nxt2 = l2; nxt3 = l3; }
  }

  if (half == 0) {
    const float v = nume * rd;
    out[(size_t)b * DIM + col] = fmaf(v, output_w[col], output_b[col]);
  }
}

extern "C" void kernel_launch(void* const* d_in, const int* in_sizes, int n_in,
                              void* d_out, int out_size, void* d_ws, size_t ws_size,
                              hipStream_t stream) {
  const float* inputs      = (const float*)d_in[0];
  const float* gleak       = (const float*)d_in[1];
  const float* vleak       = (const float*)d_in[2];
  const float* cm          = (const float*)d_in[3];
  const float* w           = (const float*)d_in[4];
  const float* sigma       = (const float*)d_in[5];
  const float* mu          = (const float*)d_in[6];
  const float* erev        = (const float*)d_in[7];
  const float* sens_w      = (const float*)d_in[8];
  const float* sens_sigma  = (const float*)d_in[9];
  const float* sens_mu     = (const float*)d_in[10];
  const float* sens_erev   = (const float*)d_in[11];
  const float* input_w     = (const float*)d_in[12];
  const float* input_b     = (const float*)d_in[13];
  const float* output_w    = (const float*)d_in[14];
  const float* output_b    = (const float*)d_in[15];

  const int B = in_sizes[0] / (T_STEPS * DIM);   // 32
  const int U = 2 * DIM;
  const int total_threads = B * U;               // 65536 = exactly 1 wave/SIMD
  dim3 block(256);
  dim3 grid(total_threads / 256);                // 256 blocks -> 1 block/CU

  memcell_kernel<<<grid, block, 0, stream>>>(
      inputs, gleak, vleak, cm, w, sigma, mu, erev,
      sens_w, sens_sigma, sens_mu, sens_erev,
      input_w, input_b, output_w, output_b, (float*)d_out);
}

// Round 3
// 123.029 us; speedup vs baseline: 1.0148x; 1.0148x over previous
//
#include <hip/hip_runtime.h>

#define T_STEPS 128
#define DIM 1024
#define ODE_UNFOLDS 6
#define EPS 1e-8f
#define L2E 1.44269504088896340736f

typedef float v2f __attribute__((ext_vector_type(2)));

__device__ __forceinline__ float fexp2(float x) { return __builtin_amdgcn_exp2f(x); }
__device__ __forceinline__ float frcp(float x)  { return __builtin_amdgcn_rcpf(x); }
__device__ __forceinline__ v2f fma2(v2f a, v2f b, v2f c) {
  return __builtin_elementwise_fma(a, b, c);   // -> v_pk_fma_f32
}

__device__ __forceinline__ float softplus_init(float x) {
  // init-only (once per thread); inputs in (0,1] so no overflow concerns
  return log2f(1.0f + exp2f(x * L2E)) * (1.0f / L2E);
}

// swap adjacent lane pairs (0<->1, 2<->3, ...): v_mov_b32_dpp quad_perm:[1,0,3,2]
__device__ __forceinline__ float swap_adj(float x) {
  int y = __builtin_amdgcn_mov_dpp(__float_as_int(x), 0xB1, 0xF, 0xF, true);
  return __int_as_float(y);
}

__global__ __launch_bounds__(256) void memcell_kernel(
    const float* __restrict__ inputs,      // (B,T,DIM)
    const float* __restrict__ gleak,       // (U)
    const float* __restrict__ vleak,       // (U)
    const float* __restrict__ cm,          // (U)
    const float* __restrict__ w,           // (U,2)
    const float* __restrict__ sigma,       // (U,2)
    const float* __restrict__ mu,          // (U,2)
    const float* __restrict__ erev,        // (U,2)
    const float* __restrict__ sens_w,      // (U)
    const float* __restrict__ sens_sigma,  // (U)
    const float* __restrict__ sens_mu,     // (U)
    const float* __restrict__ sens_erev,   // (U)
    const float* __restrict__ input_w,     // (DIM)
    const float* __restrict__ input_b,     // (DIM)
    const float* __restrict__ output_w,    // (DIM)
    const float* __restrict__ output_b,    // (DIM)
    float* __restrict__ out)               // (B,DIM)
{
  const int tid  = blockIdx.x * blockDim.x + threadIdx.x;  // [0, B*U)
  const int p    = tid >> 1;          // chain index: b*DIM + col
  const int half = tid & 1;           // 0: unit=col, 1: unit=col+DIM
  const int b    = p >> 10;           // DIM == 1024
  const int col  = p & (DIM - 1);
  const int u    = col + (half << 10);

  // ---- per-thread constants (float2 loads for the (U,2) arrays) ----
  const float2 wp  = ((const float2*)w)[u];
  const float2 sgp = ((const float2*)sigma)[u];
  const float2 mup = ((const float2*)mu)[u];
  const float2 evp = ((const float2*)erev)[u];
  const float spw0  = softplus_init(wp.x);
  const float spw1  = softplus_init(wp.y);
  const float spw0e = spw0 * evp.x;
  const float spw1e = spw1 * evp.y;
  // sigmoid((v-mu)*sg) = 1/(1 + exp2(fma(v, -sg*L2E, mu*sg*L2E)))
  const float negA0 = -sgp.x * L2E,  B0c = mup.x * sgp.x * L2E;
  const float negA1 = -sgp.y * L2E,  B1c = mup.y * sgp.y * L2E;
  // cross constants: each lane computes the exp2 its PARTNER needs
  // (partner's synapse-1 takes MY v as input, with partner's mu1/sg1)
  const float negA1x = swap_adj(negA1);
  const float B1x    = swap_adj(B1c);
  const float gl    = softplus_init(gleak[u]);
  const float glv   = gl * vleak[u];
  const float cmt   = softplus_init(cm[u]) * (float)ODE_UNFOLDS;
  const float dbase = cmt + gl + EPS;
  const float spsw  = softplus_init(sens_w[u]);
  const float ssg   = sens_sigma[u];
  const float negAs = -ssg * L2E,  Bsc = sens_mu[u] * ssg * L2E;
  const float serev = sens_erev[u];
  const float iw    = input_w[col];
  const float ib    = input_b[col];
  const v2f negApk = {negA0, negA1x};
  const v2f Bpk    = {B0c, B1x};
  const v2f spk1   = {spw1e, spw1};
  const v2f spk0   = {spw0e, spw0};

  // sensory synapse for one step: depends ONLY on x (not v) -> pipelined ahead
  auto sens = [&](float xr) -> v2f {
    const float x  = fmaf(xr, iw, ib);
    const float ts = fexp2(fmaf(x, negAs, Bsc));
    const float s  = spsw * frcp(1.0f + ts);
    v2f r; r.x = fmaf(s, serev, glv);   // glv + num_s
    r.y = dbase + s;                    // cmt + gl + eps + den_s
    return r;
  };

  const float* xp = inputs + ((size_t)b * T_STEPS) * DIM + col;

  // 8-step-deep x pipeline: cur = steps [tb..tb+3], nxt = [tb+4..tb+7]
  float cur0 = xp[0 * DIM], cur1 = xp[1 * DIM], cur2 = xp[2 * DIM], cur3 = xp[3 * DIM];
  float nxt0 = xp[4 * DIM], nxt1 = xp[5 * DIM], nxt2 = xp[6 * DIM], nxt3 = xp[7 * DIM];

  v2f nd = sens(cur0);                // {ns, ds} for step 0
  float nume = 0.0f, rd = 1.0f;       // v = nume * rd = 0

  for (int tb = 0; tb < T_STEPS; tb += 4) {
    float l0 = 0.f, l1 = 0.f, l2 = 0.f, l3 = 0.f;
    const bool more = (tb + 8) < T_STEPS;
    if (more) {
      const float* nx = xp + (size_t)(tb + 8) * DIM;
      l0 = nx[0 * DIM]; l1 = nx[1 * DIM]; l2 = nx[2 * DIM]; l3 = nx[3 * DIM];
    }
    #pragma unroll
    for (int j = 0; j < 4; ++j) {
      // x for NEXT step's sensory (independent work -> fills latency shadows)
      const float xn = (j == 0) ? cur1 : (j == 1) ? cur2 : (j == 2) ? cur3 : nxt0;
      const v2f nd_next = sens(xn);
      #pragma unroll
      for (int k = 0; k < ODE_UNFOLDS; ++k) {
        // nume-side muls issue during rcp's flight (only *rd deps remain)
        const v2f  nn   = negApk * nume;               // pk_mul
        const float cmn = cmt * nume;
        const v2f  varg = fma2(nn, (v2f){rd, rd}, Bpk);// pk_fma
        const float t0  = fexp2(varg.x);               // own syn0
        const float tc  = fexp2(varg.y);               // partner's syn1
        const float qx  = fmaf(cmn, rd, nd.x);         // cmt*v + ns
        const float t1  = swap_adj(tc);                // exchange AFTER exp2
        v2f t; t.x = t0; t.y = t1;
        const v2f a = t + 1.0f;                        // pk_add: {a0, a1}
        const float D = a.x * a.y;
        v2f P = spk1 * a.x;                            // {spw1e*a0, spw1*a0}
        P = fma2(spk0, (v2f){a.y, a.y}, P);            // {E, S}
        v2f q; q.x = qx; q.y = nd.y;                   // {numerN, ds}
        const v2f ND = fma2(q, (v2f){D, D}, P);        // {nume, deno}
        nume = ND.x;
        rd   = frcp(ND.y);
      }
      nd = nd_next;
    }
    cur0 = nxt0; cur1 = nxt1; cur2 = nxt2; cur3 = nxt3;
    if (more) { nxt0 = l0; nxt1 = l1; nxt2 = l2; nxt3 = l3; }
  }

  if (half == 0) {
    const float v = nume * rd;
    out[(size_t)b * DIM + col] = fmaf(v, output_w[col], output_b[col]);
  }
}

extern "C" void kernel_launch(void* const* d_in, const int* in_sizes, int n_in,
                              void* d_out, int out_size, void* d_ws, size_t ws_size,
                              hipStream_t stream) {
  const float* inputs      = (const float*)d_in[0];
  const float* gleak       = (const float*)d_in[1];
  const float* vleak       = (const float*)d_in[2];
  const float* cm          = (const float*)d_in[3];
  const float* w           = (const float*)d_in[4];
  const float* sigma       = (const float*)d_in[5];
  const float* mu          = (const float*)d_in[6];
  const float* erev        = (const float*)d_in[7];
  const float* sens_w      = (const float*)d_in[8];
  const float* sens_sigma  = (const float*)d_in[9];
  const float* sens_mu     = (const float*)d_in[10];
  const float* sens_erev   = (const float*)d_in[11];
  const float* input_w     = (const float*)d_in[12];
  const float* input_b     = (const float*)d_in[13];
  const float* output_w    = (const float*)d_in[14];
  const float* output_b    = (const float*)d_in[15];

  const int B = in_sizes[0] / (T_STEPS * DIM);   // 32
  const int U = 2 * DIM;
  const int total_threads = B * U;               // 65536 = exactly 1 wave/SIMD
  dim3 block(256);
  dim3 grid(total_threads / 256);                // 256 blocks -> 1 block/CU

  memcell_kernel<<<grid, block, 0, stream>>>(
      inputs, gleak, vleak, cm, w, sigma, mu, erev,
      sens_w, sens_sigma, sens_mu, sens_erev,
      input_w, input_b, output_w, output_b, (float*)d_out);
}